// Round 1
// baseline (261.822 us; speedup 1.0000x reference)
//
#include <hip/hip_runtime.h>

#define TPB 512
#define EPT 8                 // elements per thread, consecutive -> stable order
#define EPB (TPB * EPT)       // 4096 elements per block
#define NE 8                  // experts
#define NWAVE (TPB / 64)      // 8 waves == NE (wave w owns expert row w in pass-2 prologue)

typedef unsigned long long u64;
typedef unsigned int u32;
typedef int   v4i __attribute__((ext_vector_type(4)));
typedef float v4f __attribute__((ext_vector_type(4)));

// ---------------- Pass 1: per-block histogram (expert-major) + 4-bit packed key stream ----------------
__global__ __launch_bounds__(TPB) void k_hist(const int* __restrict__ idx, int M,
                                              int* __restrict__ bh, int nblocks,
                                              u32* __restrict__ kpk) {
    const int b = blockIdx.x;
    const int t = threadIdx.x;
    const long gbase = (long)b * EPB + t * EPT;

    // packed counters: lo = bins 0-3 (4 x 16b), hi = bins 4-7
    u64 lo = 0, hi = 0;
    u32 kp = 0;
    if (gbase + EPT <= M) {
        v4i v0 = *(const v4i*)(idx + gbase);
        v4i v1 = *(const v4i*)(idx + gbase + 4);
        int e[8] = {v0.x, v0.y, v0.z, v0.w, v1.x, v1.y, v1.z, v1.w};
        #pragma unroll
        for (int j = 0; j < 8; ++j) {
            kp |= ((u32)(e[j] & 7)) << (4 * j);
            u64 inc = 1ULL << ((e[j] & 3) * 16);
            if (e[j] < 4) lo += inc; else hi += inc;
        }
        kpk[(long)b * TPB + t] = kp;
    } else if (gbase < M) {
        const int nval = (int)(M - gbase);
        #pragma unroll
        for (int j = 0; j < EPT; ++j) {          // compile-time trip count: stays in registers
            if (j < nval) {
                int e = idx[gbase + j];
                kp |= ((u32)(e & 7)) << (4 * j);
                u64 inc = 1ULL << ((e & 3) * 16);
                if (e < 4) lo += inc; else hi += inc;
            }
        }
        kpk[(long)b * TPB + t] = kp;
    }

    // wave butterfly reduce (fields <= 64*8 = 512, fits 16b)
    const int lane = t & 63;
    const int wave = t >> 6;
    #pragma unroll
    for (int m = 1; m < 64; m <<= 1) {
        lo += __shfl_xor(lo, m);
        hi += __shfl_xor(hi, m);
    }
    __shared__ u64 wlo[NWAVE], whi[NWAVE];
    if (lane == 0) { wlo[wave] = lo; whi[wave] = hi; }
    __syncthreads();
    if (t < NE) {
        const int f = (t & 3) * 16;
        int tot = 0;
        #pragma unroll
        for (int wv = 0; wv < NWAVE; ++wv) {
            u64 p = (t < 4) ? wlo[wv] : whi[wv];
            tot += (int)((p >> f) & 0xFFFF);
        }
        bh[(long)t * nblocks + b] = tot;   // expert-major
    }
}

// ---------------- Pass 2: scatter with fused global scan (no separate scan kernel) ----------------
__global__ __launch_bounds__(TPB) void k_scatter(const u32* __restrict__ kpk,
                                                 const float* __restrict__ scores,
                                                 int M,
                                                 const int* __restrict__ bh, int nblocks,
                                                 float* __restrict__ outS,
                                                 float* __restrict__ outT,
                                                 float* __restrict__ outC) {
    const int b = blockIdx.x;
    const int t = threadIdx.x;
    const int lane = t & 63;
    const int wave = t >> 6;
    const long gbase = (long)b * EPB + t * EPT;

    __shared__ int sOff[NE];    // global scatter base for this block, per expert
    __shared__ int sTot[NE];    // global per-expert totals
    __shared__ u64 wlo[NWAVE], whi[NWAVE];
    __shared__ u64 lsP[EPB];    // staged {score bits:hi32 | srcpos:lo32} in sorted order

    // ---- fused scan prologue: wave w owns expert row w of bh (L2/L3-resident, 16KB/row) ----
    {
        const int* __restrict__ row = bh + (long)wave * nblocks;
        int ssum = 0, spre = 0;
        if ((nblocks & 3) == 0) {
            for (int i0 = lane * 4; i0 < nblocks; i0 += 256) {   // coalesced int4 strided
                v4i v = *(const v4i*)(row + i0);
                const int s4 = v.x + v.y + v.z + v.w;
                ssum += s4;
                if (i0 + 4 <= b) spre += s4;
                else {
                    if (i0     < b) spre += v.x;
                    if (i0 + 1 < b) spre += v.y;
                    if (i0 + 2 < b) spre += v.z;
                    if (i0 + 3 < b) spre += v.w;
                }
            }
        } else {
            for (int i = lane; i < nblocks; i += 64) {
                const int v = row[i];
                ssum += v;
                if (i < b) spre += v;
            }
        }
        #pragma unroll
        for (int m = 1; m < 64; m <<= 1) {
            ssum += __shfl_xor(ssum, m);   // row total   -> expert total
            spre += __shfl_xor(spre, m);   // sum over b' < b  -> within-expert prefix
        }
        if (lane == 0) { sTot[wave] = ssum; sOff[wave] = spre; }
    }
    __syncthreads();
    if (t < NE) {
        int base = 0;
        for (int e2 = 0; e2 < t; ++e2) base += sTot[e2];   // exclusive scan over 8 totals
        sOff[t] += base;                                   // = global base for (expert t, block b)
        if (b == 0) outC[t] = (float)sTot[t];
    }
    // sOff visibility is guaranteed by the __syncthreads after the wave-scan below.

    // ---- load scores + packed keys ----
    float sc[EPT];
    int   eidx[EPT];
    u32 kp = 0;
    int nval = 0;
    if (gbase + EPT <= M) {
        kp = kpk[(long)b * TPB + t];
        v4f s0 = *(const v4f*)(scores + gbase);
        v4f s1 = *(const v4f*)(scores + gbase + 4);
        sc[0]=s0.x; sc[1]=s0.y; sc[2]=s0.z; sc[3]=s0.w;
        sc[4]=s1.x; sc[5]=s1.y; sc[6]=s1.z; sc[7]=s1.w;
        nval = EPT;
    } else if (gbase < M) {
        kp = kpk[(long)b * TPB + t];
        nval = (int)(M - gbase);
        #pragma unroll
        for (int j = 0; j < EPT; ++j) sc[j] = (j < nval) ? scores[gbase + j] : 0.f;
    } else {
        #pragma unroll
        for (int j = 0; j < EPT; ++j) sc[j] = 0.f;
    }
    #pragma unroll
    for (int j = 0; j < EPT; ++j) eidx[j] = (int)((kp >> (4 * j)) & 7u);

    // ---- per-thread packed counts (compile-time unrolled, predicated: no scratch) ----
    u64 lo = 0, hi = 0;
    #pragma unroll
    for (int j = 0; j < EPT; ++j) {
        if (j < nval) {
            const u64 inc = 1ULL << ((eidx[j] & 3) * 16);
            if (eidx[j] < 4) lo += inc; else hi += inc;
        }
    }

    // ---- wave inclusive scan of packed counters ----
    u64 il = lo, ih = hi;
    #pragma unroll
    for (int d = 1; d < 64; d <<= 1) {
        const u64 pl = __shfl_up(il, (unsigned)d);
        const u64 ph = __shfl_up(ih, (unsigned)d);
        if (lane >= d) { il += pl; ih += ph; }
    }
    if (lane == 63) { wlo[wave] = il; whi[wave] = ih; }
    __syncthreads();

    u64 addl = 0, addh = 0;
    for (int wv = 0; wv < wave; ++wv) { addl += wlo[wv]; addh += whi[wv]; }  // shared: no scratch
    u64 rl = il - lo + addl;   // running exclusive packed offsets
    u64 rh = ih - hi + addh;

    u64 tl = 0, th = 0;
    #pragma unroll
    for (int wv = 0; wv < NWAVE; ++wv) { tl += wlo[wv]; th += whi[wv]; }

    // block-local expert bases packed into two u64s (fields <= 4096 fit 16b);
    // dynamic expert id -> variable shift extract (registers, never scratch)
    const int c0=(int)(tl & 0xFFFF), c1=(int)((tl>>16)&0xFFFF), c2=(int)((tl>>32)&0xFFFF), c3=(int)((tl>>48)&0xFFFF);
    const int c4=(int)(th & 0xFFFF), c5=(int)((th>>16)&0xFFFF), c6=(int)((th>>32)&0xFFFF), c7=(int)((th>>48)&0xFFFF);
    const int lb1=c0, lb2=lb1+c1, lb3=lb2+c2, lb4=lb3+c3, lb5=lb4+c4, lb6=lb5+c5, lb7=lb6+c6;
    const int limit = lb7 + c7;                       // total staged elements this block
    const u64 llP = ((u64)(u32)lb1 << 16) | ((u64)(u32)lb2 << 32) | ((u64)(u32)lb3 << 48);  // lb0 = 0
    const u64 lhP = ((u64)(u32)lb4) | ((u64)(u32)lb5 << 16) | ((u64)(u32)lb6 << 32) | ((u64)(u32)lb7 << 48);

    // ---- stage into LDS in final (sorted) order: one b64 write per element ----
    #pragma unroll
    for (int j = 0; j < EPT; ++j) {
        if (j < nval) {
            const int ej = eidx[j];
            const int f  = (ej & 3) * 16;
            const u64 inc = 1ULL << f;
            int off, lbj;
            if (ej < 4) { off = (int)((rl >> f) & 0xFFFF); rl += inc; lbj = (int)((llP >> f) & 0xFFFF); }
            else        { off = (int)((rh >> f) & 0xFFFF); rh += inc; lbj = (int)((lhP >> f) & 0xFFFF); }
            const int p = lbj + off;
            lsP[p] = ((u64)__float_as_uint(sc[j]) << 32) | (u32)(t * EPT + j);
        }
    }
    __syncthreads();

    // ---- parallel position-major copy-out: all threads active, coalesced within runs ----
    const int d0 = sOff[0];
    const int d1 = sOff[1] - lb1;
    const int d2 = sOff[2] - lb2;
    const int d3 = sOff[3] - lb3;
    const int d4 = sOff[4] - lb4;
    const int d5 = sOff[5] - lb5;
    const int d6 = sOff[6] - lb6;
    const int d7 = sOff[7] - lb7;
    const int tokbase = b * EPB;
    for (int p = t; p < limit; p += TPB) {
        const u64 v = lsP[p];
        int d = d0;
        if (p >= lb1) d = d1;
        if (p >= lb2) d = d2;
        if (p >= lb3) d = d3;
        if (p >= lb4) d = d4;
        if (p >= lb5) d = d5;
        if (p >= lb6) d = d6;
        if (p >= lb7) d = d7;
        const int g = p + d;
        outS[g] = __uint_as_float((u32)(v >> 32));
        outT[g] = (float)((tokbase + (int)(v & 0xFFFFFFFFu)) >> 1);   // order // TOP_K (==2)
    }
}

extern "C" void kernel_launch(void* const* d_in, const int* in_sizes, int n_in,
                              void* d_out, int out_size, void* d_ws, size_t ws_size,
                              hipStream_t stream) {
    const float* scores = (const float*)d_in[0];
    const int*   idx    = (const int*)d_in[1];
    const int M = in_sizes[1];                 // N_TOKENS * TOP_K flat keys

    float* out  = (float*)d_out;
    float* outS = out;                          // [0, M)   sorted scores
    float* outT = out + M;                      // [M, 2M)  token indices (as f32, exact < 2^24)
    float* outC = out + 2 * (long)M;            // [2M, 2M+8) expert counts

    const int nblocks = (M + EPB - 1) / EPB;    // 4096 for M = 16,777,216
    int* bh  = (int*)d_ws;                      // NE * nblocks ints, expert-major
    u32* kpk = (u32*)(bh + (long)NE * nblocks); // packed 4-bit keys, ceil(M/8) u32

    k_hist   <<<nblocks, TPB, 0, stream>>>(idx, M, bh, nblocks, kpk);
    k_scatter<<<nblocks, TPB, 0, stream>>>(kpk, scores, M, bh, nblocks, outS, outT, outC);
}